// Round 1
// 3970.130 us; speedup vs baseline: 1.2534x; 1.2534x over previous
//
#include <hip/hip_runtime.h>

#define BATCH 64
#define SEQ 8192
#define RDIM 80
#define RING 169          // max delay 168 + 1
#define NCHUNK (SEQ / 2)  // 2 steps per chunk, 1 barrier per chunk

__device__ __forceinline__ float fast_tanh(float z) {
    // tanh(z) = 1 - 2/(exp(2z)+1); exact saturation, abs err ~1e-7
    float e = __expf(2.0f * z);
    return 1.0f - 2.0f / (e + 1.0f);
}

// v + (v from lane ^ pattern) via DPP quad_perm (pure VALU, no LDS/SGPR hazard)
// 0xB1 = quad_perm(1,0,3,2) -> xor 1 ; 0x4E = quad_perm(2,3,0,1) -> xor 2
template <int CTRL>
__device__ __forceinline__ float dpp_xor_add(float v) {
    int o = __builtin_amdgcn_mov_dpp(__float_as_int(v), CTRL, 0xF, 0xF, true);
    return v + __int_as_float(o);
}

__global__ __launch_bounds__(512, 2)
void reservoir_kernel(const float* __restrict__ x,
                      const float* __restrict__ W_in,
                      const float* __restrict__ W_fb,
                      const float* __restrict__ bias,
                      float* __restrict__ out) {
    // ring[slot][i]: accumulated far-tap contributions for step s = slot (mod 169)
    __shared__ __align__(16) float ring[RING * RDIM];    // 54080 B
    // h_hist[s&3][i]: h for step s; wave0 writes, taps + wave0-broadcast read
    __shared__ __align__(16) float h_hist[4 * RDIM];     // 1280 B

    const int b    = blockIdx.x;
    const int t    = threadIdx.x;
    const int wid  = t >> 6;
    const int lane = t & 63;

    for (int i = t; i < RING * RDIM; i += 512) ring[i] = 0.0f;
    if (t < 4 * RDIM) h_hist[t] = 0.0f;

    const float* xb   = x + (size_t)b * SEQ;
    float*       outb = out + (size_t)b * (size_t)SEQ * RDIM;

    float wr[160];   // per-lane weight slice (wave0 uses first 100)

    // ---- wave-0 layout: quad q owns rows 5q..5q+4; lane (q,sub) covers j in [20*sub, 20*sub+20)
    int q = 0, sub = 0, rowA = 0, rowB = 0;
    float hA = 0.f, hB = 0.f, winA = 0.f, winB = 0.f, bA = 0.f, bB = 0.f;
    float hh[20];    // wave0: broadcast h_{s-1} slice, carried across steps
    // ---- tap layout (two step-parity triples: waves 1-3 -> par 0, waves 5-7 -> par 1)
    //      unit g = (wid-base)*64+lane < 160 ; k=g/40 -> tau{4,24,96,168};
    //      qq=(g%40)/2 -> rows 4qq..4qq+3 ; half=g&1 -> j in [40*half, 40*half+40)
    int tap_tau = 0, qq = 0, half = 0, par = 0;
    bool tap_valid = false, tap_lo = false;
    float x0 = 0.f, x1 = 0.f;

    if (wid == 0) {
        q = lane >> 2; sub = lane & 3;
        rowA = 5 * q + sub;        // owned by this lane
        rowB = 5 * q + 4;          // owned by sub==0 lane
        #pragma unroll
        for (int r = 0; r < 5; ++r) {
            const float* src = W_fb + (size_t)(5 * q + r) * RDIM + 20 * sub;  // W_1 rows
            #pragma unroll
            for (int j4 = 0; j4 < 5; ++j4) {
                float4 v = ((const float4*)src)[j4];
                wr[r * 20 + 4 * j4 + 0] = v.x; wr[r * 20 + 4 * j4 + 1] = v.y;
                wr[r * 20 + 4 * j4 + 2] = v.z; wr[r * 20 + 4 * j4 + 3] = v.w;
            }
        }
        winA = W_in[rowA]; bA = bias[rowA];
        winB = W_in[rowB]; bB = bias[rowB];
        #pragma unroll
        for (int j = 0; j < 20; ++j) hh[j] = 0.0f;   // h_{-1} = 0
        x0 = xb[0]; x1 = xb[1];
    } else if (wid != 4) {
        // wave 4 idles so wave0 owns SIMD0 alone (wid&3 SIMD mapping)
        par = (wid > 4) ? 1 : 0;
        int g = (wid - (par ? 5 : 1)) * 64 + lane;
        tap_valid = (g < 160);
        int gg = tap_valid ? g : 159;
        int k = gg / 40, rem = gg % 40;
        qq = rem >> 1; half = rem & 1;
        tap_lo = (half == 0);
        const int taus[4] = {4, 24, 96, 168};
        tap_tau = taus[k];
        #pragma unroll
        for (int r = 0; r < 4; ++r) {
            const float* src = W_fb + (size_t)(k + 1) * RDIM * RDIM
                                    + (size_t)(4 * qq + r) * RDIM + 40 * half;
            #pragma unroll
            for (int j4 = 0; j4 < 10; ++j4) {
                float4 v = ((const float4*)src)[j4];
                wr[r * 40 + 4 * j4 + 0] = v.x; wr[r * 40 + 4 * j4 + 1] = v.y;
                wr[r * 40 + 4 * j4 + 2] = v.z; wr[r * 40 + 4 * j4 + 3] = v.w;
            }
        }
    }

    __syncthreads();   // full fence once; in-loop barriers are raw s_barrier

    for (int c = 0; c < NCHUNK; ++c) {
        if (wid == 0) {
            // ================= recurrence wave: steps 2c, 2c+1 =================
            const int s0  = 2 * c;
            const int sl0 = s0 % RING, sl1 = (s0 + 1) % RING;
            // ring slots for this chunk are final (taps this chunk write slots >= 2c+2)
            float rgA0 = ring[sl0 * RDIM + rowA];
            float rgA1 = ring[sl1 * RDIM + rowA];
            float rgB0 = 0.f, rgB1 = 0.f;
            if (sub == 0) { rgB0 = ring[sl0 * RDIM + rowB]; rgB1 = ring[sl1 * RDIM + rowB]; }
            // retire the consumed slots for reuse 169 steps later
            ring[sl0 * RDIM + rowA] = 0.f; ring[sl1 * RDIM + rowA] = 0.f;
            if (sub == 0) { ring[sl0 * RDIM + rowB] = 0.f; ring[sl1 * RDIM + rowB] = 0.f; }
            // prefetch next chunk's x
            float xn0 = x0, xn1 = x1;
            if (s0 + 2 < SEQ) { xn0 = xb[s0 + 2]; xn1 = xb[s0 + 3]; }

            #pragma unroll
            for (int st = 0; st < 2; ++st) {
                const int s     = s0 + st;
                const float xs  = st ? x1   : x0;
                const float rgA = st ? rgA1 : rgA0;
                const float rgB = st ? rgB1 : rgB0;
                // hh already holds the broadcast h_{s-1} slice (prefetched last step)
                float dd[5] = {0.f, 0.f, 0.f, 0.f, 0.f};
                #pragma unroll
                for (int r = 0; r < 5; ++r)
                    #pragma unroll
                    for (int j = 0; j < 20; ++j)
                        dd[r] = fmaf(wr[r * 20 + j], hh[j], dd[r]);
                // quad all-reduce: every lane gets full dots for its quad's 5 rows
                #pragma unroll
                for (int r = 0; r < 5; ++r) {
                    dd[r] = dpp_xor_add<0xB1>(dd[r]);
                    dd[r] = dpp_xor_add<0x4E>(dd[r]);
                }
                float dA = (sub == 0) ? dd[0] : (sub == 1) ? dd[1] : (sub == 2) ? dd[2] : dd[3];
                float zA = dA + rgA + bA + xs * winA;
                hA = 0.7f * hA + 0.3f * fast_tanh(zA);
                if (sub == 0) {
                    float zB = dd[4] + rgB + bB + xs * winB;
                    hB = 0.7f * hB + 0.3f * fast_tanh(zB);
                }
                // publish h_s to LDS history (taps read it next chunk)
                h_hist[(s & 3) * RDIM + rowA] = hA;
                if (sub == 0) h_hist[(s & 3) * RDIM + rowB] = hB;
                // immediately prefetch the broadcast slice for step s+1
                // (same-wave DS ordering: reads see the writes above; only wave0 writes h_hist)
                {
                    const float4* hp = (const float4*)(h_hist + (s & 3) * RDIM + 20 * sub);
                    #pragma unroll
                    for (int j4 = 0; j4 < 5; ++j4) {
                        float4 v = hp[j4];
                        hh[4*j4+0] = v.x; hh[4*j4+1] = v.y; hh[4*j4+2] = v.z; hh[4*j4+3] = v.w;
                    }
                }
                // fire-and-forget output stores (never read by anyone; no vmcnt drain)
                outb[(size_t)s * RDIM + rowA] = hA;
                if (sub == 0) outb[(size_t)s * RDIM + rowB] = hB;
            }
            x0 = xn0; x1 = xn1;
        } else if (wid != 4 && c > 0) {
            // ===== tap triples: consume step sp = 2(c-1)+par from LDS h_hist =====
            const int sp = 2 * (c - 1) + par;
            const float* hp = h_hist + (sp & 3) * RDIM + 40 * half;
            float ha[40];
            #pragma unroll
            for (int j4 = 0; j4 < 10; ++j4) {
                float4 v = ((const float4*)hp)[j4];
                ha[4*j4+0] = v.x; ha[4*j4+1] = v.y; ha[4*j4+2] = v.z; ha[4*j4+3] = v.w;
            }
            float dA[4] = {0.f, 0.f, 0.f, 0.f};
            #pragma unroll
            for (int r = 0; r < 4; ++r)
                #pragma unroll
                for (int j = 0; j < 40; ++j)
                    dA[r] = fmaf(wr[r * 40 + j], ha[j], dA[r]);
            // combine j-halves across the (even,odd) lane pair
            #pragma unroll
            for (int r = 0; r < 4; ++r)
                dA[r] = dpp_xor_add<0xB1>(dA[r]);
            if (tap_valid && tap_lo) {
                const int sl = (sp + tap_tau) % RING;
                float4* pA = (float4*)(ring + sl * RDIM + 4 * qq);
                float4 vA = *pA;
                vA.x += dA[0]; vA.y += dA[1]; vA.z += dA[2]; vA.w += dA[3];
                *pA = vA;
            }
        }
        // LDS-only fence + raw barrier: do NOT drain vmcnt (global stores in flight)
        asm volatile("s_waitcnt lgkmcnt(0)" ::: "memory");
        __builtin_amdgcn_s_barrier();
    }
}

extern "C" void kernel_launch(void* const* d_in, const int* in_sizes, int n_in,
                              void* d_out, int out_size, void* d_ws, size_t ws_size,
                              hipStream_t stream) {
    const float* x    = (const float*)d_in[0];   // (64, 8192, 1)
    const float* W_in = (const float*)d_in[1];   // (80, 1)
    const float* W_fb = (const float*)d_in[2];   // (5, 80, 80)
    const float* bias = (const float*)d_in[3];   // (80,)
    float* out        = (float*)d_out;           // (64, 8192, 80)

    reservoir_kernel<<<BATCH, 512, 0, stream>>>(x, W_in, W_fb, bias, out);
}

// Round 2
// 3387.053 us; speedup vs baseline: 1.4692x; 1.1721x over previous
//
#include <hip/hip_runtime.h>

#define BATCH 64
#define SEQ 8192
#define RDIM 80
#define RING 169          // max delay 168 + 1
#define NCHUNK (SEQ / 2)  // 2 steps per chunk, 1 barrier per chunk

typedef float v2f __attribute__((ext_vector_type(2)));

__device__ __forceinline__ float fast_tanh(float z) {
    // tanh(z) = 1 - 2/(exp(2z)+1); exact saturation, abs err ~1e-7
    float e = __expf(2.0f * z);
    return 1.0f - 2.0f / (e + 1.0f);
}

// v + (v from lane ^ pattern) via DPP quad_perm (pure VALU, no LDS/SGPR hazard)
// 0xB1 = quad_perm(1,0,3,2) -> xor 1 ; 0x4E = quad_perm(2,3,0,1) -> xor 2
template <int CTRL>
__device__ __forceinline__ float dpp_xor_add(float v) {
    int o = __builtin_amdgcn_mov_dpp(__float_as_int(v), CTRL, 0xF, 0xF, true);
    return v + __int_as_float(o);
}

// min-waves=1: 512-thread block already forces 2 waves/SIMD -> 256-VGPR cap.
// (512,2) capped at 128 VGPRs and pushed wr[] into AGPR shuffle traffic.
__global__ __launch_bounds__(512, 1)
void reservoir_kernel(const float* __restrict__ x,
                      const float* __restrict__ W_in,
                      const float* __restrict__ W_fb,
                      const float* __restrict__ bias,
                      float* __restrict__ out) {
    // ring[slot][i]: accumulated far-tap contributions for step s = slot (mod 169)
    __shared__ __align__(16) float ring[RING * RDIM];    // 54080 B
    // h_hist[s&3][i]: h for step s; wave0 writes, taps + wave0-broadcast read
    __shared__ __align__(16) float h_hist[4 * RDIM];     // 1280 B

    const int b    = blockIdx.x;
    const int t    = threadIdx.x;
    const int wid  = t >> 6;
    const int lane = t & 63;

    for (int i = t; i < RING * RDIM; i += 512) ring[i] = 0.0f;
    if (t < 4 * RDIM) h_hist[t] = 0.0f;

    const float* xb   = x + (size_t)b * SEQ;
    float*       outb = out + (size_t)b * (size_t)SEQ * RDIM;

    v2f wr2[80];   // per-lane weight slice as packed pairs (wave0 uses first 50)

    // ---- wave-0 layout: quad q owns rows 5q..5q+4; lane (q,sub) covers j in [20*sub, 20*sub+20)
    int q = 0, sub = 0, rowA = 0, rowB = 0;
    float hA = 0.f, hB = 0.f, winA = 0.f, winB = 0.f, bA = 0.f, bB = 0.f;
    v2f hh2[10];   // wave0: broadcast h_{s-1} slice (packed), carried across steps
    // ---- tap layout (two step-parity triples: waves 1-3 -> par 0, waves 5-7 -> par 1)
    //      unit g = (wid-base)*64+lane < 160 ; k=g/40 -> tau{4,24,96,168};
    //      qq=(g%40)/2 -> rows 4qq..4qq+3 ; half=g&1 -> j in [40*half, 40*half+40)
    int tap_tau = 0, qq = 0, half = 0, par = 0;
    bool tap_valid = false, tap_lo = false;
    float x0 = 0.f, x1 = 0.f;

    if (wid == 0) {
        q = lane >> 2; sub = lane & 3;
        rowA = 5 * q + sub;        // owned by this lane
        rowB = 5 * q + 4;          // owned by sub==0 lane
        #pragma unroll
        for (int r = 0; r < 5; ++r) {
            const float* src = W_fb + (size_t)(5 * q + r) * RDIM + 20 * sub;  // W_1 rows
            #pragma unroll
            for (int j4 = 0; j4 < 5; ++j4) {
                float4 v = ((const float4*)src)[j4];
                wr2[r * 10 + 2 * j4 + 0] = (v2f){v.x, v.y};
                wr2[r * 10 + 2 * j4 + 1] = (v2f){v.z, v.w};
            }
        }
        winA = W_in[rowA]; bA = bias[rowA];
        winB = W_in[rowB]; bB = bias[rowB];
        #pragma unroll
        for (int j2 = 0; j2 < 10; ++j2) hh2[j2] = (v2f){0.f, 0.f};   // h_{-1} = 0
        x0 = xb[0]; x1 = xb[1];
    } else if (wid != 4) {
        // wave 4 idles so wave0 owns SIMD0 alone (wid&3 SIMD mapping)
        par = (wid > 4) ? 1 : 0;
        int g = (wid - (par ? 5 : 1)) * 64 + lane;
        tap_valid = (g < 160);
        int gg = tap_valid ? g : 159;
        int k = gg / 40, rem = gg % 40;
        qq = rem >> 1; half = rem & 1;
        tap_lo = (half == 0);
        const int taus[4] = {4, 24, 96, 168};
        tap_tau = taus[k];
        #pragma unroll
        for (int r = 0; r < 4; ++r) {
            const float* src = W_fb + (size_t)(k + 1) * RDIM * RDIM
                                    + (size_t)(4 * qq + r) * RDIM + 40 * half;
            #pragma unroll
            for (int j4 = 0; j4 < 10; ++j4) {
                float4 v = ((const float4*)src)[j4];
                wr2[r * 20 + 2 * j4 + 0] = (v2f){v.x, v.y};
                wr2[r * 20 + 2 * j4 + 1] = (v2f){v.z, v.w};
            }
        }
    }

    __syncthreads();   // full fence once; in-loop barriers are raw s_barrier

    for (int c = 0; c < NCHUNK; ++c) {
        if (wid == 0) {
            // ================= recurrence wave: steps 2c, 2c+1 =================
            const int s0  = 2 * c;
            const int sl0 = s0 % RING, sl1 = (s0 + 1) % RING;
            // ring slots for this chunk are final (taps this chunk write slots >= 2c+2)
            float rgA0 = ring[sl0 * RDIM + rowA];
            float rgA1 = ring[sl1 * RDIM + rowA];
            float rgB0 = 0.f, rgB1 = 0.f;
            if (sub == 0) { rgB0 = ring[sl0 * RDIM + rowB]; rgB1 = ring[sl1 * RDIM + rowB]; }
            // retire the consumed slots for reuse 169 steps later
            ring[sl0 * RDIM + rowA] = 0.f; ring[sl1 * RDIM + rowA] = 0.f;
            if (sub == 0) { ring[sl0 * RDIM + rowB] = 0.f; ring[sl1 * RDIM + rowB] = 0.f; }
            // prefetch next chunk's x (8B aligned: s0+2 even)
            float xn0 = x0, xn1 = x1;
            if (s0 + 2 < SEQ) { float2 xn = *(const float2*)(xb + s0 + 2); xn0 = xn.x; xn1 = xn.y; }

            #pragma unroll
            for (int st = 0; st < 2; ++st) {
                const int s     = s0 + st;
                const float xs  = st ? x1   : x0;
                const float rgA = st ? rgA1 : rgA0;
                const float rgB = st ? rgB1 : rgB0;
                // hh2 already holds the broadcast h_{s-1} slice (prefetched last step)
                v2f dd2[5];
                #pragma unroll
                for (int r = 0; r < 5; ++r) dd2[r] = (v2f){0.f, 0.f};
                #pragma unroll
                for (int r = 0; r < 5; ++r)
                    #pragma unroll
                    for (int j2 = 0; j2 < 10; ++j2)
                        dd2[r] = __builtin_elementwise_fma(wr2[r * 10 + j2], hh2[j2], dd2[r]);
                float dd[5];
                #pragma unroll
                for (int r = 0; r < 5; ++r) dd[r] = dd2[r].x + dd2[r].y;
                // quad all-reduce: every lane gets full dots for its quad's 5 rows
                #pragma unroll
                for (int r = 0; r < 5; ++r) {
                    dd[r] = dpp_xor_add<0xB1>(dd[r]);
                    dd[r] = dpp_xor_add<0x4E>(dd[r]);
                }
                float dA = (sub == 0) ? dd[0] : (sub == 1) ? dd[1] : (sub == 2) ? dd[2] : dd[3];
                float zA = dA + rgA + bA + xs * winA;
                hA = 0.7f * hA + 0.3f * fast_tanh(zA);
                if (sub == 0) {
                    float zB = dd[4] + rgB + bB + xs * winB;
                    hB = 0.7f * hB + 0.3f * fast_tanh(zB);
                }
                // publish h_s to LDS history (taps read it next chunk)
                h_hist[(s & 3) * RDIM + rowA] = hA;
                if (sub == 0) h_hist[(s & 3) * RDIM + rowB] = hB;
                // immediately prefetch the broadcast slice for step s+1
                // (same-wave DS ordering: reads see the writes above; only wave0 writes h_hist)
                {
                    const float4* hp = (const float4*)(h_hist + (s & 3) * RDIM + 20 * sub);
                    #pragma unroll
                    for (int j4 = 0; j4 < 5; ++j4) {
                        float4 v = hp[j4];
                        hh2[2 * j4 + 0] = (v2f){v.x, v.y};
                        hh2[2 * j4 + 1] = (v2f){v.z, v.w};
                    }
                }
                // fire-and-forget output stores (never read by anyone; no vmcnt drain)
                outb[(size_t)s * RDIM + rowA] = hA;
                if (sub == 0) outb[(size_t)s * RDIM + rowB] = hB;
            }
            x0 = xn0; x1 = xn1;
        } else if (wid != 4 && c > 0) {
            // ===== tap triples: consume step sp = 2(c-1)+par from LDS h_hist =====
            const int sp = 2 * (c - 1) + par;
            const float* hp = h_hist + (sp & 3) * RDIM + 40 * half;
            v2f ha2[20];
            #pragma unroll
            for (int j4 = 0; j4 < 10; ++j4) {
                float4 v = ((const float4*)hp)[j4];
                ha2[2 * j4 + 0] = (v2f){v.x, v.y};
                ha2[2 * j4 + 1] = (v2f){v.z, v.w};
            }
            v2f dA2[4];
            #pragma unroll
            for (int r = 0; r < 4; ++r) dA2[r] = (v2f){0.f, 0.f};
            #pragma unroll
            for (int r = 0; r < 4; ++r)
                #pragma unroll
                for (int j2 = 0; j2 < 20; ++j2)
                    dA2[r] = __builtin_elementwise_fma(wr2[r * 20 + j2], ha2[j2], dA2[r]);
            float dA[4];
            #pragma unroll
            for (int r = 0; r < 4; ++r) dA[r] = dA2[r].x + dA2[r].y;
            // combine j-halves across the (even,odd) lane pair
            #pragma unroll
            for (int r = 0; r < 4; ++r)
                dA[r] = dpp_xor_add<0xB1>(dA[r]);
            if (tap_valid && tap_lo) {
                const int sl = (sp + tap_tau) % RING;
                float4* pA = (float4*)(ring + sl * RDIM + 4 * qq);
                float4 vA = *pA;
                vA.x += dA[0]; vA.y += dA[1]; vA.z += dA[2]; vA.w += dA[3];
                *pA = vA;
            }
        }
        // LDS-only fence + raw barrier: do NOT drain vmcnt (global stores in flight)
        asm volatile("s_waitcnt lgkmcnt(0)" ::: "memory");
        __builtin_amdgcn_s_barrier();
    }
}

extern "C" void kernel_launch(void* const* d_in, const int* in_sizes, int n_in,
                              void* d_out, int out_size, void* d_ws, size_t ws_size,
                              hipStream_t stream) {
    const float* x    = (const float*)d_in[0];   // (64, 8192, 1)
    const float* W_in = (const float*)d_in[1];   // (80, 1)
    const float* W_fb = (const float*)d_in[2];   // (5, 80, 80)
    const float* bias = (const float*)d_in[3];   // (80,)
    float* out        = (float*)d_out;           // (64, 8192, 80)

    reservoir_kernel<<<BATCH, 512, 0, stream>>>(x, W_in, W_fb, bias, out);
}